// Round 1
// baseline (51677.850 us; speedup 1.0000x reference)
//
#include <hip/hip_runtime.h>
#include <math.h>

#define LB 64      // batch
#define LT 2048    // timesteps
#define LH 256     // hidden
#define LOUT 256
#define K2 512     // fused K: 256 (x) + 256 (h)
#define NROWS 1024 // 4*H gate rows

// ---------------------------------------------------------------------------
// Prologue: transpose+reorder weights into k-major layout, fuse biases.
// Wt[(l*512 + k)*1024 + ridx]  where ridx = slice*64 + gate*16 + jj
// maps original row = gate*256 + slice*16 + jj;  k<256 -> W_ih, k>=256 -> W_hh
// ---------------------------------------------------------------------------
__global__ void prep_weights(const float* __restrict__ W_ih,
                             const float* __restrict__ W_hh,
                             const float* __restrict__ b_ih,
                             const float* __restrict__ b_hh,
                             float* __restrict__ Wt,
                             float* __restrict__ bias_r) {
    int g = blockIdx.x * blockDim.x + threadIdx.x;
    if (g >= 2 * K2 * NROWS) return;
    int ridx = g & (NROWS - 1);
    int k    = (g >> 10) & (K2 - 1);
    int l    = g >> 19;
    int s = ridx >> 6, r6 = ridx & 63, gate = r6 >> 4, jj = r6 & 15;
    int row = gate * LH + s * 16 + jj;
    float v;
    if (k < LH) v = W_ih[(size_t)(l * NROWS + row) * LH + k];
    else        v = W_hh[(size_t)(l * NROWS + row) * LH + (k - LH)];
    Wt[g] = v;  // g == ((l*K2 + k)*NROWS + ridx)
    if (k == 0) bias_r[l * NROWS + ridx] = b_ih[l * NROWS + row] + b_hh[l * NROWS + row];
}

// ---------------------------------------------------------------------------
// One timestep, both layers pipelined diagonally:
//   blocks 0..127  : layer 0 at t = r        (active if r < T)
//   blocks 128..255: layer 1 at t = r - 1    (active if r >= 1)
// Each block: 8 batch elems x 16 hidden cols (64 gate rows).
// Wave w (of 4) handles batch pair {2w, 2w+1}; lane = gate row within slice.
// ---------------------------------------------------------------------------
__global__ __launch_bounds__(256)
void lstm_step(const float* __restrict__ x,
               const float* __restrict__ Wt,
               const float* __restrict__ bias_r,
               float* __restrict__ h1,   // [2][B][H] ping-pong
               float* __restrict__ h2,   // [2][B][H] ping-pong
               float* __restrict__ c1,   // [B][H]
               float* __restrict__ c2,   // [B][H]
               int r) {
    int wg = blockIdx.x;
    int layer = wg >> 7;
    if (layer == 0) { if (r >= LT) return; }
    else            { if (r <  1) return; }
    int t = (layer == 0) ? r : r - 1;

    int g  = wg & 127;
    int bg = g & 7;         // batch group
    int s  = g >> 3;        // hidden slice (0..15)
    int b0 = bg * 8;

    __shared__ float in_s[K2][9];     // [k][batch] transposed, padded (bank-safe)
    __shared__ float gates_s[8][64];

    int tid = threadIdx.x;
    int kmax = (t > 0) ? K2 : LH;

    // stage inputs: x-part (or lower-layer h), k-major into LDS
    for (int idx = tid; idx < 8 * LH; idx += 256) {
        int bl = idx >> 8, k = idx & 255;
        float v;
        if (layer == 0) v = x[((size_t)(b0 + bl) * LT + t) * LH + k];
        else            v = h1[(size_t)(t & 1) * LB * LH + (b0 + bl) * LH + k];
        in_s[k][bl] = v;
    }
    if (t > 0) {
        const float* hp = (layer == 0 ? h1 : h2) + (size_t)((t - 1) & 1) * LB * LH;
        for (int idx = tid; idx < 8 * LH; idx += 256) {
            int bl = idx >> 8, k = idx & 255;
            in_s[LH + k][bl] = hp[(b0 + bl) * LH + k];
        }
    }
    __syncthreads();

    int lane = tid & 63, wave = tid >> 6;
    int ridx = s * 64 + lane;
    const float* wp = Wt + (size_t)layer * K2 * NROWS + ridx;
    float bias = bias_r[layer * NROWS + ridx];
    float acc0 = bias, acc1 = bias;
    int bA = wave * 2, bB = bA + 1;

#pragma unroll 8
    for (int k = 0; k < kmax; ++k) {
        float w = wp[(size_t)k * NROWS];        // coalesced 256B per wave
        acc0 = fmaf(w, in_s[k][bA], acc0);      // LDS broadcast reads
        acc1 = fmaf(w, in_s[k][bB], acc1);
    }
    gates_s[bA][lane] = acc0;
    gates_s[bB][lane] = acc1;
    __syncthreads();

    if (tid < 128) {
        int bl = tid >> 4, jj = tid & 15;
        float gi = gates_s[bl][jj];
        float gf = gates_s[bl][16 + jj];
        float gg = gates_s[bl][32 + jj];
        float go = gates_s[bl][48 + jj];
        int jglob = s * 16 + jj;
        float* cbuf = (layer == 0 ? c1 : c2);
        int ci = (b0 + bl) * LH + jglob;
        float cold = (t > 0) ? cbuf[ci] : 0.f;
        float si = 1.f / (1.f + expf(-gi));
        float sf = 1.f / (1.f + expf(-gf));
        float so = 1.f / (1.f + expf(-go));
        float cn = sf * cold + si * tanhf(gg);
        float hn = so * tanhf(cn);
        cbuf[ci] = cn;
        float* hout = (layer == 0 ? h1 : h2) + (size_t)(t & 1) * LB * LH;
        hout[ci] = hn;
    }
}

// ---------------------------------------------------------------------------
// Epilogue: out = h2_last @ W_fc^T + b_fc
// ---------------------------------------------------------------------------
__global__ __launch_bounds__(256)
void fc_kernel(const float* __restrict__ h2_last,
               const float* __restrict__ W_fc,
               const float* __restrict__ b_fc,
               float* __restrict__ out) {
    int b = blockIdx.x;
    int o = threadIdx.x;
    __shared__ float hrow[LH];
    for (int k = threadIdx.x; k < LH; k += blockDim.x)
        hrow[k] = h2_last[b * LH + k];
    __syncthreads();
    float acc = b_fc[o];
#pragma unroll 8
    for (int k = 0; k < LH; ++k)
        acc = fmaf(W_fc[o * LH + k], hrow[k], acc);
    out[b * LOUT + o] = acc;
}

extern "C" void kernel_launch(void* const* d_in, const int* in_sizes, int n_in,
                              void* d_out, int out_size, void* d_ws, size_t ws_size,
                              hipStream_t stream) {
    const float* x    = (const float*)d_in[0];
    const float* W_ih = (const float*)d_in[1];
    const float* W_hh = (const float*)d_in[2];
    const float* b_ih = (const float*)d_in[3];
    const float* b_hh = (const float*)d_in[4];
    const float* W_fc = (const float*)d_in[5];
    const float* b_fc = (const float*)d_in[6];
    float* out = (float*)d_out;

    char* ws = (char*)d_ws;
    float* Wt     = (float*)ws;                               // 2*512*1024*4 = 4 MB
    float* bias_r = (float*)(ws + (size_t)4 * 1024 * 1024);   // 8 KB
    float* h1     = bias_r + 2 * NROWS;                       // 2*64*256 floats
    float* h2     = h1 + 2 * LB * LH;
    float* c1     = h2 + 2 * LB * LH;
    float* c2     = c1 + LB * LH;

    prep_weights<<<(2 * K2 * NROWS) / 256, 256, 0, stream>>>(W_ih, W_hh, b_ih, b_hh, Wt, bias_r);

    for (int r = 0; r <= LT; ++r)
        lstm_step<<<256, 256, 0, stream>>>(x, Wt, bias_r, h1, h2, c1, c2, r);

    // last timestep t = 2047 -> slot 1
    fc_kernel<<<LB, 256, 0, stream>>>(h2 + (size_t)1 * LB * LH, W_fc, b_fc, out);
}

// Round 2
// 50362.628 us; speedup vs baseline: 1.0261x; 1.0261x over previous
//
#include <hip/hip_runtime.h>
#include <math.h>

#define LB 64
#define LT 2048
#define LH 256
#define LOUT 256
#define K2 512
#define NROWS 1024
#define NWG 256
#define ISTR 12           // padded floats per k-row in LDS input tile
#define CNT_STRIDE 16     // ints per round (64 B)

// ---------- ws layout (bytes) ----------
#define WS_CNT      0
#define WS_CNT_SZ   ((size_t)(LT + 1) * CNT_STRIDE * sizeof(int))  // 131136
#define WS_BIAS     (140 * 1024)
#define WS_H1       (152 * 1024)                 // 2 slots * 64*256*4 = 131072
#define WS_H2       (WS_H1 + 131072)
#define WS_WT       (WS_H2 + 131072)             // 4 MB

// ---------------------------------------------------------------------------
// Prologue: transpose+reorder weights k-major, fuse biases.
// Wt[(l*512 + k)*1024 + ridx], ridx = slice*64 + gate*16 + jj
// original row = gate*256 + slice*16 + jj ; k<256 -> W_ih, k>=256 -> W_hh
// ---------------------------------------------------------------------------
__global__ void prep_weights(const float* __restrict__ W_ih,
                             const float* __restrict__ W_hh,
                             const float* __restrict__ b_ih,
                             const float* __restrict__ b_hh,
                             float* __restrict__ Wt,
                             float* __restrict__ bias_r) {
    int g = blockIdx.x * blockDim.x + threadIdx.x;
    if (g >= 2 * K2 * NROWS) return;
    int ridx = g & (NROWS - 1);
    int k    = (g >> 10) & (K2 - 1);
    int l    = g >> 19;
    int s = ridx >> 6, r6 = ridx & 63, gate = r6 >> 4, jj = r6 & 15;
    int row = gate * LH + s * 16 + jj;
    float v;
    if (k < LH) v = W_ih[(size_t)(l * NROWS + row) * LH + k];
    else        v = W_hh[(size_t)(l * NROWS + row) * LH + (k - LH)];
    Wt[g] = v;
    if (k == 0) bias_r[l * NROWS + ridx] = b_ih[l * NROWS + row] + b_hh[l * NROWS + row];
}

// ---------------------------------------------------------------------------
// Persistent 2-layer LSTM. 256 WGs (128 per layer), 1 per CU.
// WG (layer, bg, s): 8 batches (b0..b0+7) x 64 gate-rows (slice s).
// Weights (128 KB) LDS-resident. Grid barrier per round via agent atomics.
// Layer 0 computes t=r; layer 1 computes t=r-1 (diagonal pipeline).
// ---------------------------------------------------------------------------
__global__ __launch_bounds__(256, 1)
void lstm_persistent(const float* __restrict__ x,
                     const float* __restrict__ Wt,
                     const float* __restrict__ bias_r,
                     float* __restrict__ h1g,
                     float* __restrict__ h2g,
                     int* __restrict__ cnt)
{
    __shared__ __align__(16) float w_lds[K2 * 64];   // 128 KB
    __shared__ __align__(16) float un[K2 * ISTR];    // 24 KB: in_s / partials union
    __shared__ float bias_lds[64];

    const int tid   = threadIdx.x;
    const int wg    = blockIdx.x;
    const int layer = wg >> 7;
    const int g     = wg & 127;
    const int b0    = (g & 7) * 8;   // batch group
    const int s     = g >> 3;        // row slice
    const int lane  = tid & 63;
    const int wave  = tid >> 6;

    // ---- one-time: weights + bias into LDS ----
    {
        const float* wsrc = Wt + (size_t)layer * K2 * NROWS + s * 64;
        for (int it = tid; it < K2 * 16; it += 256) {
            int k = it >> 4, q = it & 15;
            float4 v = *(const float4*)(wsrc + (size_t)k * NROWS + q * 4);
            *(float4*)&w_lds[k * 64 + q * 4] = v;
        }
        if (tid < 64) bias_lds[tid] = bias_r[layer * NROWS + s * 64 + tid];
    }

    // x prefetch registers (layer 0): two float4 items per thread per step
    const int i0b = tid & 7, i0k = tid >> 3;       // kq 0..31
    const int i1k = i0k + 32;                      // kq 32..63
    float4 xr0 = make_float4(0, 0, 0, 0), xr1 = xr0;
    if (layer == 0) {
        xr0 = *(const float4*)(x + ((size_t)(b0 + i0b) * LT + 0) * LH + i0k * 4);
        xr1 = *(const float4*)(x + ((size_t)(b0 + i0b) * LT + 0) * LH + i1k * 4);
    }

    float c_reg = 0.f;                   // cell state, owned by tid<128
    const int myb = tid >> 4, myj = tid & 15;

    __syncthreads();

    for (int r = 0; r <= LT; ++r) {
        const bool active = (layer == 0) ? (r < LT) : (r >= 1);
        const int t = (layer == 0) ? r : (r - 1);

        // ---- stage inputs into un[k][b] (stride ISTR) ----
        if (active) {
            if (layer == 0) {
                {   // prefetched x registers -> LDS
                    float* d0 = &un[(i0k * 4) * ISTR + i0b];
                    d0[0] = xr0.x; d0[ISTR] = xr0.y; d0[2*ISTR] = xr0.z; d0[3*ISTR] = xr0.w;
                    float* d1 = &un[(i1k * 4) * ISTR + i0b];
                    d1[0] = xr1.x; d1[ISTR] = xr1.y; d1[2*ISTR] = xr1.z; d1[3*ISTR] = xr1.w;
                }
                if (t + 1 < LT) {   // prefetch next timestep (no barrier dependency)
                    xr0 = *(const float4*)(x + ((size_t)(b0 + i0b) * LT + (t + 1)) * LH + i0k * 4);
                    xr1 = *(const float4*)(x + ((size_t)(b0 + i0b) * LT + (t + 1)) * LH + i1k * 4);
                }
                if (t > 0) {        // own-layer recurrent h
                    const float* hp = h1g + (size_t)((t - 1) & 1) * LB * LH;
                    for (int it = tid; it < 512; it += 256) {
                        int b = it & 7, kq = it >> 3;
                        float4 v = *(const float4*)(hp + (size_t)(b0 + b) * LH + kq * 4);
                        float* d = &un[(256 + kq * 4) * ISTR + b];
                        d[0] = v.x; d[ISTR] = v.y; d[2*ISTR] = v.z; d[3*ISTR] = v.w;
                    }
                }
            } else {
                const float* hp = h1g + (size_t)(t & 1) * LB * LH;   // lower-layer input
                for (int it = tid; it < 512; it += 256) {
                    int b = it & 7, kq = it >> 3;
                    float4 v = *(const float4*)(hp + (size_t)(b0 + b) * LH + kq * 4);
                    float* d = &un[(kq * 4) * ISTR + b];
                    d[0] = v.x; d[ISTR] = v.y; d[2*ISTR] = v.z; d[3*ISTR] = v.w;
                }
                if (t > 0) {        // own-layer recurrent h
                    const float* hq = h2g + (size_t)((t - 1) & 1) * LB * LH;
                    for (int it = tid; it < 512; it += 256) {
                        int b = it & 7, kq = it >> 3;
                        float4 v = *(const float4*)(hq + (size_t)(b0 + b) * LH + kq * 4);
                        float* d = &un[(256 + kq * 4) * ISTR + b];
                        d[0] = v.x; d[ISTR] = v.y; d[2*ISTR] = v.z; d[3*ISTR] = v.w;
                    }
                }
            }
        }
        __syncthreads();   // in_s ready

        // ---- GEMM slice: wave w does k in [w*128, w*128+128), 8 batches ----
        float a0=0,a1=0,a2=0,a3=0,a4=0,a5=0,a6=0,a7=0;
        if (active && !(t == 0 && wave >= 2)) {   // t==0: no h-part (k>=256)
            const int kbeg = wave * 128;
            const float* wl = &w_lds[kbeg * 64 + lane];
            const float* il = &un[kbeg * ISTR];
            #pragma unroll 4
            for (int k = 0; k < 128; ++k) {
                float w = wl[k * 64];                          // conflict-free
                float4 iA = *(const float4*)(il + k * ISTR);   // broadcast
                float4 iB = *(const float4*)(il + k * ISTR + 4);
                a0 = fmaf(w, iA.x, a0); a1 = fmaf(w, iA.y, a1);
                a2 = fmaf(w, iA.z, a2); a3 = fmaf(w, iA.w, a3);
                a4 = fmaf(w, iB.x, a4); a5 = fmaf(w, iB.y, a5);
                a6 = fmaf(w, iB.z, a6); a7 = fmaf(w, iB.w, a7);
            }
        }
        // partials into own k-quarter of un (safe: only this wave read those rows)
        if (active) {
            float* dst = &un[wave * 1536 + lane * ISTR];
            *(float4*)dst       = make_float4(a0, a1, a2, a3);
            *(float4*)(dst + 4) = make_float4(a4, a5, a6, a7);
        }
        __syncthreads();   // partials ready

        // ---- reduce + nonlinearity + h store (tid<128: (b,myj)) ----
        if (active && tid < 128) {
            float gi = bias_lds[myj];
            float gf = bias_lds[16 + myj];
            float gG = bias_lds[32 + myj];
            float go = bias_lds[48 + myj];
            #pragma unroll
            for (int w = 0; w < 4; ++w) {
                const float* rw = &un[w * 1536 + myb];
                gi += rw[myj * ISTR];
                gf += rw[(16 + myj) * ISTR];
                gG += rw[(32 + myj) * ISTR];
                go += rw[(48 + myj) * ISTR];
            }
            float si = 1.f / (1.f + expf(-gi));
            float sf = 1.f / (1.f + expf(-gf));
            float so = 1.f / (1.f + expf(-go));
            float cn = sf * c_reg + si * tanhf(gG);
            float hn = so * tanhf(cn);
            c_reg = cn;
            float* hout = (layer == 0 ? h1g : h2g) + (size_t)(t & 1) * LB * LH;
            // L2-bypassing store -> coherence point; visible after peers' acquire
            __hip_atomic_store(hout + (size_t)(b0 + myb) * LH + s * 16 + myj, hn,
                               __ATOMIC_RELAXED, __HIP_MEMORY_SCOPE_AGENT);
        }

        // ---- grid barrier (rounds 0..LT-1) ----
        if (r < LT) {
            __syncthreads();   // drains vmem: h stores at coherence point
            if (tid == 0) {
                int* base = cnt + (size_t)r * CNT_STRIDE;
                __hip_atomic_fetch_add(base + (wg & 7), 1,
                                       __ATOMIC_RELEASE, __HIP_MEMORY_SCOPE_AGENT);
                int sum = 0;
                do {
                    sum = 0;
                    #pragma unroll
                    for (int i = 0; i < 8; ++i)
                        sum += __hip_atomic_load(base + i, __ATOMIC_RELAXED,
                                                 __HIP_MEMORY_SCOPE_AGENT);
                    if (sum < NWG) __builtin_amdgcn_s_sleep(1);
                } while (sum < NWG);
            }
            __syncthreads();
            __builtin_amdgcn_fence(__ATOMIC_ACQUIRE, "agent");  // L2 inv: see peers' h
        }
    }
}

// ---------------------------------------------------------------------------
// Epilogue: out = h2_last @ W_fc^T + b_fc
// ---------------------------------------------------------------------------
__global__ __launch_bounds__(256)
void fc_kernel(const float* __restrict__ h2_last,
               const float* __restrict__ W_fc,
               const float* __restrict__ b_fc,
               float* __restrict__ out) {
    int b = blockIdx.x;
    int o = threadIdx.x;
    __shared__ float hrow[LH];
    for (int k = threadIdx.x; k < LH; k += blockDim.x)
        hrow[k] = h2_last[b * LH + k];
    __syncthreads();
    float acc = b_fc[o];
#pragma unroll 8
    for (int k = 0; k < LH; ++k)
        acc = fmaf(W_fc[o * LH + k], hrow[k], acc);
    out[b * LOUT + o] = acc;
}

extern "C" void kernel_launch(void* const* d_in, const int* in_sizes, int n_in,
                              void* d_out, int out_size, void* d_ws, size_t ws_size,
                              hipStream_t stream) {
    const float* x    = (const float*)d_in[0];
    const float* W_ih = (const float*)d_in[1];
    const float* W_hh = (const float*)d_in[2];
    const float* b_ih = (const float*)d_in[3];
    const float* b_hh = (const float*)d_in[4];
    const float* W_fc = (const float*)d_in[5];
    const float* b_fc = (const float*)d_in[6];
    float* out = (float*)d_out;

    char* ws = (char*)d_ws;
    int*   cnt    = (int*)(ws + WS_CNT);
    float* bias_r = (float*)(ws + WS_BIAS);
    float* h1g    = (float*)(ws + WS_H1);
    float* h2g    = (float*)(ws + WS_H2);
    float* Wt     = (float*)(ws + WS_WT);

    hipMemsetAsync(cnt, 0, WS_CNT_SZ, stream);   // barrier counters fresh each call
    prep_weights<<<(2 * K2 * NROWS) / 256, 256, 0, stream>>>(W_ih, W_hh, b_ih, b_hh, Wt, bias_r);

    void* args[] = {(void*)&x, (void*)&Wt, (void*)&bias_r,
                    (void*)&h1g, (void*)&h2g, (void*)&cnt};
    hipError_t e = hipLaunchCooperativeKernel(lstm_persistent, dim3(NWG), dim3(256),
                                              args, 0, stream);
    if (e != hipSuccess) {
        // GPU is otherwise idle and LDS caps at 1 WG/CU: 256 WGs co-reside anyway
        lstm_persistent<<<NWG, 256, 0, stream>>>(x, Wt, bias_r, h1g, h2g, cnt);
    }

    fc_kernel<<<LB, 256, 0, stream>>>(h2g + (size_t)1 * LB * LH, W_fc, b_fc, out);
}

// Round 3
// 14017.723 us; speedup vs baseline: 3.6866x; 3.5928x over previous
//
#include <hip/hip_runtime.h>
#include <math.h>

#define LB 64
#define LT 2048
#define LH 256
#define LOUT 256
#define K2 512
#define NROWS 1024
#define NWG 256
#define ISTR 12            // padded floats per k-row in LDS input tile
#define GSTRIDE 2112       // ints per sync group (8448 B, no line sharing)
#define GROUP_N 32         // WGs per sync group (16 layer0 + 16 layer1)

// ---------- ws layout (bytes) ----------
#define WS_CNT      0
#define WS_CNT_SZ   ((size_t)8 * GSTRIDE * sizeof(int))   // 67584
#define WS_BIAS     (140 * 1024)
#define WS_H1       (152 * 1024)                 // 2 slots * 64*256*4 = 131072
#define WS_H2       (WS_H1 + 131072)
#define WS_WT       (WS_H2 + 131072)             // 4 MB

typedef unsigned long long u64;

__device__ __forceinline__ float2 ld_f2_ic(const float* p) {
    u64 u = __hip_atomic_load((const u64*)p, __ATOMIC_RELAXED,
                              __HIP_MEMORY_SCOPE_AGENT);
    union { u64 u; float2 f; } c; c.u = u;
    return c.f;
}

// ---------------------------------------------------------------------------
// Prologue: transpose+reorder weights k-major, fuse biases.
// Wt[(l*512 + k)*1024 + ridx], ridx = slice*64 + gate*16 + jj
// original row = gate*256 + slice*16 + jj ; k<256 -> W_ih, k>=256 -> W_hh
// ---------------------------------------------------------------------------
__global__ void prep_weights(const float* __restrict__ W_ih,
                             const float* __restrict__ W_hh,
                             const float* __restrict__ b_ih,
                             const float* __restrict__ b_hh,
                             float* __restrict__ Wt,
                             float* __restrict__ bias_r) {
    int g = blockIdx.x * blockDim.x + threadIdx.x;
    if (g >= 2 * K2 * NROWS) return;
    int ridx = g & (NROWS - 1);
    int k    = (g >> 10) & (K2 - 1);
    int l    = g >> 19;
    int s = ridx >> 6, r6 = ridx & 63, gate = r6 >> 4, jj = r6 & 15;
    int row = gate * LH + s * 16 + jj;
    float v;
    if (k < LH) v = W_ih[(size_t)(l * NROWS + row) * LH + k];
    else        v = W_hh[(size_t)(l * NROWS + row) * LH + (k - LH)];
    Wt[g] = v;
    if (k == 0) bias_r[l * NROWS + ridx] = b_ih[l * NROWS + row] + b_hh[l * NROWS + row];
}

// ---------------------------------------------------------------------------
// Persistent 2-layer LSTM. 256 WGs (128/layer), 1/CU, weights LDS-resident.
// Sync: per-batch-group (bg) groups of 32 WGs; relaxed agent atomics only
// (no wbl2/inv cache maintenance). h traffic bypasses L1/L2 via sc1 atomics.
// ---------------------------------------------------------------------------
__global__ __launch_bounds__(256, 1)
void lstm_persistent(const float* __restrict__ x,
                     const float* __restrict__ Wt,
                     const float* __restrict__ bias_r,
                     float* __restrict__ h1g,
                     float* __restrict__ h2g,
                     int* __restrict__ cnt)
{
    __shared__ __align__(16) float w_lds[K2 * 64];   // 128 KB
    __shared__ __align__(16) float un[K2 * ISTR];    // 24 KB: in_s / partials union
    __shared__ float bias_lds[64];

    const int tid   = threadIdx.x;
    const int wg    = blockIdx.x;
    const int layer = wg >> 7;
    const int g     = wg & 127;
    const int b0    = (g & 7) * 8;   // batch group
    const int s     = g >> 3;        // row slice
    const int lane  = tid & 63;
    const int wave  = tid >> 6;
    int* const flag_base = cnt + (size_t)(wg & 7) * GSTRIDE;

    // ---- one-time: weights + bias into LDS ----
    {
        const float* wsrc = Wt + (size_t)layer * K2 * NROWS + s * 64;
        for (int it = tid; it < K2 * 16; it += 256) {
            int k = it >> 4, q = it & 15;
            float4 v = *(const float4*)(wsrc + (size_t)k * NROWS + q * 4);
            *(float4*)&w_lds[k * 64 + q * 4] = v;
        }
        if (tid < 64) bias_lds[tid] = bias_r[layer * NROWS + s * 64 + tid];
    }

    // x prefetch registers (layer 0): two float4 items per thread per step
    const int i0b = tid & 7, i0k = tid >> 3;       // kq 0..31
    const int i1k = i0k + 32;                      // kq 32..63
    float4 xr0 = make_float4(0, 0, 0, 0), xr1 = xr0;
    if (layer == 0) {
        xr0 = *(const float4*)(x + ((size_t)(b0 + i0b) * LT + 0) * LH + i0k * 4);
        xr1 = *(const float4*)(x + ((size_t)(b0 + i0b) * LT + 0) * LH + i1k * 4);
    }

    float c_reg = 0.f;                   // cell state, owned by tid<128
    const int myb = tid >> 4, myj = tid & 15;

    __syncthreads();

    for (int r = 0; r <= LT; ++r) {
        const bool active = (layer == 0) ? (r < LT) : (r >= 1);
        const int t = (layer == 0) ? r : (r - 1);

        // ---- stage inputs into un[k][b] (stride ISTR) ----
        if (active) {
            if (layer == 0) {
                {   // prefetched x registers -> LDS
                    float* d0 = &un[(i0k * 4) * ISTR + i0b];
                    d0[0] = xr0.x; d0[ISTR] = xr0.y; d0[2*ISTR] = xr0.z; d0[3*ISTR] = xr0.w;
                    float* d1 = &un[(i1k * 4) * ISTR + i0b];
                    d1[0] = xr1.x; d1[ISTR] = xr1.y; d1[2*ISTR] = xr1.z; d1[3*ISTR] = xr1.w;
                }
                if (t + 1 < LT) {   // prefetch next timestep (no barrier dependency)
                    xr0 = *(const float4*)(x + ((size_t)(b0 + i0b) * LT + (t + 1)) * LH + i0k * 4);
                    xr1 = *(const float4*)(x + ((size_t)(b0 + i0b) * LT + (t + 1)) * LH + i1k * 4);
                }
                if (t > 0) {        // own-layer recurrent h (IC-coherent loads)
                    const float* hp = h1g + (size_t)((t - 1) & 1) * LB * LH;
                    for (int it = tid; it < 512; it += 256) {
                        int b = it & 7, kq = it >> 3;
                        const float* src = hp + (size_t)(b0 + b) * LH + kq * 4;
                        float2 f0 = ld_f2_ic(src);
                        float2 f1 = ld_f2_ic(src + 2);
                        float* d = &un[(256 + kq * 4) * ISTR + b];
                        d[0] = f0.x; d[ISTR] = f0.y; d[2*ISTR] = f1.x; d[3*ISTR] = f1.y;
                    }
                }
            } else {
                const float* hp = h1g + (size_t)(t & 1) * LB * LH;   // lower-layer input
                for (int it = tid; it < 512; it += 256) {
                    int b = it & 7, kq = it >> 3;
                    const float* src = hp + (size_t)(b0 + b) * LH + kq * 4;
                    float2 f0 = ld_f2_ic(src);
                    float2 f1 = ld_f2_ic(src + 2);
                    float* d = &un[(kq * 4) * ISTR + b];
                    d[0] = f0.x; d[ISTR] = f0.y; d[2*ISTR] = f1.x; d[3*ISTR] = f1.y;
                }
                if (t > 0) {        // own-layer recurrent h
                    const float* hq = h2g + (size_t)((t - 1) & 1) * LB * LH;
                    for (int it = tid; it < 512; it += 256) {
                        int b = it & 7, kq = it >> 3;
                        const float* src = hq + (size_t)(b0 + b) * LH + kq * 4;
                        float2 f0 = ld_f2_ic(src);
                        float2 f1 = ld_f2_ic(src + 2);
                        float* d = &un[(256 + kq * 4) * ISTR + b];
                        d[0] = f0.x; d[ISTR] = f0.y; d[2*ISTR] = f1.x; d[3*ISTR] = f1.y;
                    }
                }
            }
        }
        __syncthreads();   // in_s ready

        // ---- GEMM slice: wave w does k in [w*128, w*128+128), 8 batches ----
        float a0=0,a1=0,a2=0,a3=0,a4=0,a5=0,a6=0,a7=0;
        if (active && !(t == 0 && wave >= 2)) {   // t==0: no h-part (k>=256)
            const int kbeg = wave * 128;
            const float* wl = &w_lds[kbeg * 64 + lane];
            const float* il = &un[kbeg * ISTR];
            #pragma unroll 4
            for (int k = 0; k < 128; ++k) {
                float w = wl[k * 64];                          // conflict-free
                float4 iA = *(const float4*)(il + k * ISTR);   // broadcast
                float4 iB = *(const float4*)(il + k * ISTR + 4);
                a0 = fmaf(w, iA.x, a0); a1 = fmaf(w, iA.y, a1);
                a2 = fmaf(w, iA.z, a2); a3 = fmaf(w, iA.w, a3);
                a4 = fmaf(w, iB.x, a4); a5 = fmaf(w, iB.y, a5);
                a6 = fmaf(w, iB.z, a6); a7 = fmaf(w, iB.w, a7);
            }
        }
        // partials into own k-quarter of un (safe: only this wave read those rows)
        if (active) {
            float* dst = &un[wave * 1536 + lane * ISTR];
            *(float4*)dst       = make_float4(a0, a1, a2, a3);
            *(float4*)(dst + 4) = make_float4(a4, a5, a6, a7);
        }
        __syncthreads();   // partials ready

        // ---- reduce + nonlinearity + h store (tid<128: (b,myj)) ----
        if (active && tid < 128) {
            float gi = bias_lds[myj];
            float gf = bias_lds[16 + myj];
            float gG = bias_lds[32 + myj];
            float go = bias_lds[48 + myj];
            #pragma unroll
            for (int w = 0; w < 4; ++w) {
                const float* rw = &un[w * 1536 + myb];
                gi += rw[myj * ISTR];
                gf += rw[(16 + myj) * ISTR];
                gG += rw[(32 + myj) * ISTR];
                go += rw[(48 + myj) * ISTR];
            }
            float si = 1.f / (1.f + expf(-gi));
            float sf = 1.f / (1.f + expf(-gf));
            float so = 1.f / (1.f + expf(-go));
            float cn = sf * c_reg + si * tanhf(gG);
            float hn = so * tanhf(cn);
            c_reg = cn;
            float* hout = (layer == 0 ? h1g : h2g) + (size_t)(t & 1) * LB * LH;
            // IC-coherent store (sc1): visible to peers' IC loads, no fence needed
            __hip_atomic_store(hout + (size_t)(b0 + myb) * LH + s * 16 + myj, hn,
                               __ATOMIC_RELAXED, __HIP_MEMORY_SCOPE_AGENT);
        }

        // ---- per-group barrier (rounds 0..LT-1), relaxed atomics only ----
        if (r < LT) {
            __syncthreads();   // per-thread vmcnt(0) before s_barrier: h stores acked
            if (tid == 0) {
                int* flag = flag_base + r;
                __hip_atomic_fetch_add(flag, 1, __ATOMIC_RELAXED,
                                       __HIP_MEMORY_SCOPE_AGENT);
                while (__hip_atomic_load(flag, __ATOMIC_RELAXED,
                                         __HIP_MEMORY_SCOPE_AGENT) < GROUP_N)
                    __builtin_amdgcn_s_sleep(1);
            }
            __syncthreads();
        }
    }
}

// ---------------------------------------------------------------------------
// Epilogue: out = h2_last @ W_fc^T + b_fc
// ---------------------------------------------------------------------------
__global__ __launch_bounds__(256)
void fc_kernel(const float* __restrict__ h2_last,
               const float* __restrict__ W_fc,
               const float* __restrict__ b_fc,
               float* __restrict__ out) {
    int b = blockIdx.x;
    int o = threadIdx.x;
    __shared__ float hrow[LH];
    for (int k = threadIdx.x; k < LH; k += blockDim.x)
        hrow[k] = h2_last[b * LH + k];
    __syncthreads();
    float acc = b_fc[o];
#pragma unroll 8
    for (int k = 0; k < LH; ++k)
        acc = fmaf(W_fc[o * LH + k], hrow[k], acc);
    out[b * LOUT + o] = acc;
}

extern "C" void kernel_launch(void* const* d_in, const int* in_sizes, int n_in,
                              void* d_out, int out_size, void* d_ws, size_t ws_size,
                              hipStream_t stream) {
    const float* x    = (const float*)d_in[0];
    const float* W_ih = (const float*)d_in[1];
    const float* W_hh = (const float*)d_in[2];
    const float* b_ih = (const float*)d_in[3];
    const float* b_hh = (const float*)d_in[4];
    const float* W_fc = (const float*)d_in[5];
    const float* b_fc = (const float*)d_in[6];
    float* out = (float*)d_out;

    char* ws = (char*)d_ws;
    int*   cnt    = (int*)(ws + WS_CNT);
    float* bias_r = (float*)(ws + WS_BIAS);
    float* h1g    = (float*)(ws + WS_H1);
    float* h2g    = (float*)(ws + WS_H2);
    float* Wt     = (float*)(ws + WS_WT);

    hipMemsetAsync(cnt, 0, WS_CNT_SZ, stream);   // fresh barrier counters each call
    prep_weights<<<(2 * K2 * NROWS) / 256, 256, 0, stream>>>(W_ih, W_hh, b_ih, b_hh, Wt, bias_r);

    void* args[] = {(void*)&x, (void*)&Wt, (void*)&bias_r,
                    (void*)&h1g, (void*)&h2g, (void*)&cnt};
    hipError_t e = hipLaunchCooperativeKernel(lstm_persistent, dim3(NWG), dim3(256),
                                              args, 0, stream);
    if (e != hipSuccess) {
        // GPU otherwise idle and LDS caps at 1 WG/CU: 256 WGs co-reside anyway
        lstm_persistent<<<NWG, 256, 0, stream>>>(x, Wt, bias_r, h1g, h2g, cnt);
    }

    fc_kernel<<<LB, 256, 0, stream>>>(h2g + (size_t)1 * LB * LH, W_fc, b_fc, out);
}

// Round 4
// 11906.597 us; speedup vs baseline: 4.3403x; 1.1773x over previous
//
#include <hip/hip_runtime.h>
#include <math.h>

typedef unsigned long long u64;
typedef __attribute__((ext_vector_type(8))) short short8v;   // 8 bf16 = 4 VGPR
typedef __attribute__((ext_vector_type(4))) float f32x4;

#define LB 64
#define LT 2048
#define LH 256
#define LOUT 256
#define NWG 256
#define GSTRIDE 2112       // ints per sync group
#define GROUP_N 32         // WGs per sync group (same batch-group, both layers)

// ---------- ws layout (bytes) ----------
#define WS_CNT    0
#define WS_CNT_SZ ((size_t)8 * GSTRIDE * sizeof(int))
#define WS_H1HI   (128 * 1024)   // each h array: 2 slots*64*256 bf16 = 64 KB
#define WS_H1LO   (192 * 1024)
#define WS_H2HI   (256 * 1024)
#define WS_H2LO   (320 * 1024)
#define WS_BIAS   (384 * 1024)   // 2*1024 fp32 = 8 KB
#define WS_WT2    (512 * 1024)   // 2^21 bf16 = 4 MB

#define MFMA(a, b, c) __builtin_amdgcn_mfma_f32_16x16x32_bf16(a, b, c, 0, 0, 0)

__device__ __host__ __forceinline__ short bf16_rne(float f) {
    unsigned u = __builtin_bit_cast(unsigned, f);
    unsigned r = (u + 0x7fffu + ((u >> 16) & 1u)) >> 16;
    return (short)r;
}
__device__ __forceinline__ float bf16_to_f(short s) {
    unsigned u = ((unsigned)(unsigned short)s) << 16;
    return __builtin_bit_cast(float, u);
}

// ---------------------------------------------------------------------------
// Prologue: split weights into hi/lo bf16 MFMA A-fragments.
// Frag for (layer, s, mt, ks): lane l holds W[row = mt*256 + s*16 + (l&15)]
//                                      [k = ks*32 + (l>>4)*8 + j], j=0..7.
// Wt2 elem offset = (((layer*16+s)*4+mt)*16+ks)*1024 + term*512 + kg*128 + rw*8 + j
// ---------------------------------------------------------------------------
__global__ void prep_weights(const float* __restrict__ W_ih,
                             const float* __restrict__ W_hh,
                             const float* __restrict__ b_ih,
                             const float* __restrict__ b_hh,
                             unsigned short* __restrict__ Wt2,
                             float* __restrict__ bias_r) {
    int gid = blockIdx.x * 256 + threadIdx.x;       // 2^20 positions
    if (gid >= (1 << 20)) return;
    int j   = gid & 7;
    int rwi = (gid >> 3) & 15;
    int kgi = (gid >> 7) & 3;
    int ks  = (gid >> 9) & 15;
    int mt  = (gid >> 13) & 3;
    int s   = (gid >> 15) & 15;
    int layer = gid >> 19;
    int k   = ks * 32 + kgi * 8 + j;
    int row = mt * 256 + s * 16 + rwi;              // original gate row
    float w = (k < 256) ? W_ih[((size_t)layer * 1024 + row) * 256 + k]
                        : W_hh[((size_t)layer * 1024 + row) * 256 + (k - 256)];
    short hi = bf16_rne(w);
    float rem = w - bf16_to_f(hi);
    short lo = bf16_rne(rem);
    size_t base = (((size_t)((layer * 16 + s) * 4 + mt) * 16 + ks) * 1024)
                  + (size_t)kgi * 128 + rwi * 8 + j;
    Wt2[base]       = (unsigned short)hi;
    Wt2[base + 512] = (unsigned short)lo;
    if (k == 0) {
        int ridx = s * 64 + mt * 16 + rwi;
        bias_r[layer * 1024 + ridx] = b_ih[layer * 1024 + row] + b_hh[layer * 1024 + row];
    }
}

// ---------------------------------------------------------------------------
// Persistent 2-layer LSTM, MFMA split-bf16. 256 WGs (128/layer), 1/CU.
// WG (layer, bg, s): 64 gate-rows (slice s) x 8 batches x K=512.
// Waves k-split (128 k each). Weights in VGPRs. B-frags direct from IC.
// ---------------------------------------------------------------------------
__global__ __launch_bounds__(256, 1)
void lstm_persistent(const float* __restrict__ x,
                     const unsigned short* __restrict__ Wt2,
                     const float* __restrict__ bias_r,
                     u64* __restrict__ h1hi, u64* __restrict__ h1lo,
                     u64* __restrict__ h2hi, u64* __restrict__ h2lo,
                     int* __restrict__ cnt)
{
    __shared__ __align__(16) f32x4 red[12][64];    // cross-wave partials, 12 KB

    const int tid   = threadIdx.x;
    const int wg    = blockIdx.x;
    const int layer = wg >> 7;
    const int g     = wg & 127;
    const int bg    = g & 7;
    const int s     = g >> 3;
    const int b0    = bg * 8;
    const int wave  = tid >> 6;
    const int lane  = tid & 63;
    const int kg    = lane >> 4;       // k-group within frag
    const int rw    = lane & 15;       // row-within-tile / batch col
    const int rb    = rw & 7;          // duplicated batch for lanes 8..15
    const int batch = b0 + rb;
    int* const flag_base = cnt + (size_t)bg * GSTRIDE;

    // ---- one-time: A-fragments (weights) into registers ----
    short8v Ahi[4][4], Alo[4][4];      // [mt][kstep-within-wave]
    #pragma unroll
    for (int mt = 0; mt < 4; ++mt)
        #pragma unroll
        for (int k2 = 0; k2 < 4; ++k2) {
            size_t base = (((size_t)((layer * 16 + s) * 4 + mt) * 16 + (wave * 4 + k2)) * 1024)
                          + (size_t)kg * 128 + rw * 8;
            Ahi[mt][k2] = *(const short8v*)((const short*)Wt2 + base);
            Alo[mt][k2] = *(const short8v*)((const short*)Wt2 + base + 512);
        }

    f32x4 biasv[4];
    #pragma unroll
    for (int mt = 0; mt < 4; ++mt)
        biasv[mt] = *(const f32x4*)(bias_r + layer * 1024 + s * 64 + mt * 16 + kg * 4);

    f32x4 creg = {0.f, 0.f, 0.f, 0.f};             // cell state (wave 0, rw<8)

    for (int r = 0; r <= LT; ++r) {
        const bool active = (layer == 0) ? (r < LT) : (r >= 1);
        const int t = (layer == 0) ? r : (r - 1);

        f32x4 acc[4];
        #pragma unroll
        for (int mt = 0; mt < 4; ++mt) acc[mt] = (f32x4){0.f, 0.f, 0.f, 0.f};

        if (active) {
            #pragma unroll
            for (int k2 = 0; k2 < 4; ++k2) {
                const int ks = wave * 4 + k2;
                const int kbase = ks * 32 + kg * 8;
                short8v bhi, blo;
                bool skip = false;
                if (ks < 8) {
                    // -------- input part: x (L0) or h1(t) (L1) --------
                    if (layer == 0) {
                        const float* xp = x + ((size_t)batch * LT + t) * LH + kbase;
                        float4 v0 = *(const float4*)xp;
                        float4 v1 = *(const float4*)(xp + 4);
                        float fv[8] = {v0.x, v0.y, v0.z, v0.w, v1.x, v1.y, v1.z, v1.w};
                        #pragma unroll
                        for (int j = 0; j < 8; ++j) {
                            short hb = bf16_rne(fv[j]);
                            bhi[j] = hb;
                            blo[j] = bf16_rne(fv[j] - bf16_to_f(hb));
                        }
                    } else {
                        size_t qi = (size_t)(t & 1) * 4096 + (size_t)batch * 64 + (kbase >> 2);
                        union { u64 q[2]; short8v v; } ch, cl;
                        ch.q[0] = __hip_atomic_load(h1hi + qi,     __ATOMIC_RELAXED, __HIP_MEMORY_SCOPE_AGENT);
                        ch.q[1] = __hip_atomic_load(h1hi + qi + 1, __ATOMIC_RELAXED, __HIP_MEMORY_SCOPE_AGENT);
                        cl.q[0] = __hip_atomic_load(h1lo + qi,     __ATOMIC_RELAXED, __HIP_MEMORY_SCOPE_AGENT);
                        cl.q[1] = __hip_atomic_load(h1lo + qi + 1, __ATOMIC_RELAXED, __HIP_MEMORY_SCOPE_AGENT);
                        bhi = ch.v; blo = cl.v;
                    }
                } else {
                    // -------- recurrent part: own h(t-1) --------
                    if (t == 0) { skip = true; bhi = (short8v)0; blo = (short8v)0; }
                    else {
                        const int hb = kbase - 256;
                        const u64* ph = (layer == 0 ? h1hi : h2hi);
                        const u64* pl = (layer == 0 ? h1lo : h2lo);
                        size_t qi = (size_t)((t - 1) & 1) * 4096 + (size_t)batch * 64 + (hb >> 2);
                        union { u64 q[2]; short8v v; } ch, cl;
                        ch.q[0] = __hip_atomic_load(ph + qi,     __ATOMIC_RELAXED, __HIP_MEMORY_SCOPE_AGENT);
                        ch.q[1] = __hip_atomic_load(ph + qi + 1, __ATOMIC_RELAXED, __HIP_MEMORY_SCOPE_AGENT);
                        cl.q[0] = __hip_atomic_load(pl + qi,     __ATOMIC_RELAXED, __HIP_MEMORY_SCOPE_AGENT);
                        cl.q[1] = __hip_atomic_load(pl + qi + 1, __ATOMIC_RELAXED, __HIP_MEMORY_SCOPE_AGENT);
                        bhi = ch.v; blo = cl.v;
                    }
                }
                if (!skip) {
                    #pragma unroll
                    for (int mt = 0; mt < 4; ++mt) {
                        acc[mt] = MFMA(Ahi[mt][k2], bhi, acc[mt]);  // hi*hi
                        acc[mt] = MFMA(Ahi[mt][k2], blo, acc[mt]);  // hi*lo
                        acc[mt] = MFMA(Alo[mt][k2], bhi, acc[mt]);  // lo*hi
                    }
                }
            }
        }

        // ---- cross-wave k-reduction via LDS ----
        if (active && wave > 0) {
            #pragma unroll
            for (int mt = 0; mt < 4; ++mt) red[(wave - 1) * 4 + mt][lane] = acc[mt];
        }
        __syncthreads();

        if (active && wave == 0) {
            f32x4 gate[4];
            #pragma unroll
            for (int mt = 0; mt < 4; ++mt) {
                f32x4 gs = acc[mt] + biasv[mt];
                #pragma unroll
                for (int w = 0; w < 3; ++w) gs += red[w * 4 + mt][lane];
                gate[mt] = gs;
            }
            // lane holds gates i,f,g,o (mt=0..3) for batch rw, hid = s*16+kg*4+rr
            float hv[4];
            #pragma unroll
            for (int rr = 0; rr < 4; ++rr) {
                float si = 1.f / (1.f + expf(-gate[0][rr]));
                float sf = 1.f / (1.f + expf(-gate[1][rr]));
                float so = 1.f / (1.f + expf(-gate[3][rr]));
                float gg = tanhf(gate[2][rr]);
                float cn = sf * creg[rr] + si * gg;
                creg[rr] = cn;
                hv[rr] = so * tanhf(cn);
            }
            if (rw < 8) {
                u64 qh = 0, ql = 0;
                #pragma unroll
                for (int rr = 0; rr < 4; ++rr) {
                    short hb = bf16_rne(hv[rr]);
                    short lb = bf16_rne(hv[rr] - bf16_to_f(hb));
                    qh |= ((u64)(unsigned short)hb) << (16 * rr);
                    ql |= ((u64)(unsigned short)lb) << (16 * rr);
                }
                u64* dh = (layer == 0 ? h1hi : h2hi);
                u64* dl = (layer == 0 ? h1lo : h2lo);
                size_t qi = (size_t)(t & 1) * 4096 + (size_t)(b0 + rw) * 64 + (s * 4 + kg);
                __hip_atomic_store(dh + qi, qh, __ATOMIC_RELAXED, __HIP_MEMORY_SCOPE_AGENT);
                __hip_atomic_store(dl + qi, ql, __ATOMIC_RELAXED, __HIP_MEMORY_SCOPE_AGENT);
            }
        }

        // ---- per-group barrier (rounds 0..LT-1), relaxed atomics only ----
        if (r < LT) {
            __syncthreads();   // drains vmem incl. wave0's h stores
            if (tid == 0) {
                int* flag = flag_base + r;
                __hip_atomic_fetch_add(flag, 1, __ATOMIC_RELAXED, __HIP_MEMORY_SCOPE_AGENT);
                while (__hip_atomic_load(flag, __ATOMIC_RELAXED, __HIP_MEMORY_SCOPE_AGENT) < GROUP_N)
                    __builtin_amdgcn_s_sleep(1);
            }
            __syncthreads();
        }
    }
}

// ---------------------------------------------------------------------------
// Epilogue: out = h2(2047) @ W_fc^T + b_fc   (h2 reconstructed from hi+lo)
// ---------------------------------------------------------------------------
__global__ __launch_bounds__(256)
void fc_kernel(const unsigned short* __restrict__ h2hi_s,
               const unsigned short* __restrict__ h2lo_s,
               const float* __restrict__ W_fc,
               const float* __restrict__ b_fc,
               float* __restrict__ out) {
    int b = blockIdx.x;
    int o = threadIdx.x;
    __shared__ float hrow[LH];
    for (int k = threadIdx.x; k < LH; k += 256) {
        int idx = 16384 /*slot1*/ + b * 256 + k;
        hrow[k] = bf16_to_f((short)h2hi_s[idx]) + bf16_to_f((short)h2lo_s[idx]);
    }
    __syncthreads();
    float acc = b_fc[o];
#pragma unroll 8
    for (int k = 0; k < LH; ++k)
        acc = fmaf(W_fc[o * LH + k], hrow[k], acc);
    out[b * LOUT + o] = acc;
}

extern "C" void kernel_launch(void* const* d_in, const int* in_sizes, int n_in,
                              void* d_out, int out_size, void* d_ws, size_t ws_size,
                              hipStream_t stream) {
    const float* x    = (const float*)d_in[0];
    const float* W_ih = (const float*)d_in[1];
    const float* W_hh = (const float*)d_in[2];
    const float* b_ih = (const float*)d_in[3];
    const float* b_hh = (const float*)d_in[4];
    const float* W_fc = (const float*)d_in[5];
    const float* b_fc = (const float*)d_in[6];
    float* out = (float*)d_out;

    char* ws = (char*)d_ws;
    int*            cnt    = (int*)(ws + WS_CNT);
    u64*            h1hi   = (u64*)(ws + WS_H1HI);
    u64*            h1lo   = (u64*)(ws + WS_H1LO);
    u64*            h2hi   = (u64*)(ws + WS_H2HI);
    u64*            h2lo   = (u64*)(ws + WS_H2LO);
    float*          bias_r = (float*)(ws + WS_BIAS);
    unsigned short* Wt2    = (unsigned short*)(ws + WS_WT2);

    hipMemsetAsync(cnt, 0, WS_CNT_SZ, stream);   // fresh barrier counters each call
    prep_weights<<<(1 << 20) / 256, 256, 0, stream>>>(W_ih, W_hh, b_ih, b_hh, Wt2, bias_r);

    void* args[] = {(void*)&x, (void*)&Wt2, (void*)&bias_r,
                    (void*)&h1hi, (void*)&h1lo, (void*)&h2hi, (void*)&h2lo, (void*)&cnt};
    hipError_t e = hipLaunchCooperativeKernel(lstm_persistent, dim3(NWG), dim3(256),
                                              args, 0, stream);
    if (e != hipSuccess) {
        // GPU otherwise idle, 1 WG/CU: 256 WGs co-reside anyway
        lstm_persistent<<<NWG, 256, 0, stream>>>(x, Wt2, bias_r, h1hi, h1lo, h2hi, h2lo, cnt);
    }

    fc_kernel<<<LB, 256, 0, stream>>>((const unsigned short*)h2hi,
                                      (const unsigned short*)h2lo, W_fc, b_fc, out);
}

// Round 5
// 10820.670 us; speedup vs baseline: 4.7758x; 1.1004x over previous
//
#include <hip/hip_runtime.h>
#include <math.h>

typedef unsigned long long u64;
typedef __attribute__((ext_vector_type(8))) short short8v;   // 8 bf16 = 4 VGPR
typedef __attribute__((ext_vector_type(4))) float f32x4;

#define LB 64
#define LT 2048
#define LH 256
#define LOUT 256
#define NWG 256

// ---------- ws layout (bytes) ----------
#define WS_CNT    0
#define WS_CNT_SZ ((size_t)8 * 64 * sizeof(int))   // 8 bg * 32 flags (+pad)
#define WS_H1HI   (128 * 1024)   // each h array: 2 slots*64*256 bf16 = 64 KB
#define WS_H1LO   (192 * 1024)
#define WS_H2HI   (256 * 1024)
#define WS_H2LO   (320 * 1024)
#define WS_BIAS   (384 * 1024)   // 2*1024 fp32 = 8 KB
#define WS_WT2    (512 * 1024)   // 2^21 bf16 = 4 MB

#define MFMA(a, b, c) __builtin_amdgcn_mfma_f32_16x16x32_bf16(a, b, c, 0, 0, 0)
#define LD_IC(p) __hip_atomic_load((p), __ATOMIC_RELAXED, __HIP_MEMORY_SCOPE_AGENT)
#define ST_IC(p, v) __hip_atomic_store((p), (v), __ATOMIC_RELAXED, __HIP_MEMORY_SCOPE_AGENT)

__device__ __host__ __forceinline__ short bf16_rne(float f) {
    unsigned u = __builtin_bit_cast(unsigned, f);
    unsigned r = (u + 0x7fffu + ((u >> 16) & 1u)) >> 16;
    return (short)r;
}
__device__ __forceinline__ float bf16_to_f(short s) {
    unsigned u = ((unsigned)(unsigned short)s) << 16;
    return __builtin_bit_cast(float, u);
}
// fast sigmoid/tanh: v_exp_f32 (2^x) + v_rcp_f32; rel err ~1e-6, negligible here
__device__ __forceinline__ float fsigm(float g) {
    return __builtin_amdgcn_rcpf(1.f + __builtin_amdgcn_exp2f(g * -1.44269504f));
}
__device__ __forceinline__ float ftanh(float g) {
    return __builtin_amdgcn_rcpf(1.f + __builtin_amdgcn_exp2f(g * -2.88539008f)) * 2.f - 1.f;
}

// ---------------------------------------------------------------------------
// Prologue: split weights into hi/lo bf16 MFMA A-fragments.
// Frag for (layer, s, mt, ks): lane l holds W[row = mt*256 + s*16 + (l&15)]
//                                      [k = ks*32 + (l>>4)*8 + j], j=0..7.
// Wt2 elem offset = (((layer*16+s)*4+mt)*16+ks)*1024 + term*512 + kg*128 + rw*8 + j
// ---------------------------------------------------------------------------
__global__ void prep_weights(const float* __restrict__ W_ih,
                             const float* __restrict__ W_hh,
                             const float* __restrict__ b_ih,
                             const float* __restrict__ b_hh,
                             unsigned short* __restrict__ Wt2,
                             float* __restrict__ bias_r) {
    int gid = blockIdx.x * 256 + threadIdx.x;       // 2^20 positions
    if (gid >= (1 << 20)) return;
    int j   = gid & 7;
    int rwi = (gid >> 3) & 15;
    int kgi = (gid >> 7) & 3;
    int ks  = (gid >> 9) & 15;
    int mt  = (gid >> 13) & 3;
    int s   = (gid >> 15) & 15;
    int layer = gid >> 19;
    int k   = ks * 32 + kgi * 8 + j;
    int row = mt * 256 + s * 16 + rwi;              // original gate row
    float w = (k < 256) ? W_ih[((size_t)layer * 1024 + row) * 256 + k]
                        : W_hh[((size_t)layer * 1024 + row) * 256 + (k - 256)];
    short hi = bf16_rne(w);
    float rem = w - bf16_to_f(hi);
    short lo = bf16_rne(rem);
    size_t base = (((size_t)((layer * 16 + s) * 4 + mt) * 16 + ks) * 1024)
                  + (size_t)kgi * 128 + rwi * 8 + j;
    Wt2[base]       = (unsigned short)hi;
    Wt2[base + 512] = (unsigned short)lo;
    if (k == 0) {
        int ridx = s * 64 + mt * 16 + rwi;
        bias_r[layer * 1024 + ridx] = b_ih[layer * 1024 + row] + b_hh[layer * 1024 + row];
    }
}

// ---------------------------------------------------------------------------
// Persistent 2-layer LSTM, MFMA split-bf16. 256 WGs (128/layer), 1/CU.
// WG (layer, bg, s): 64 gate-rows (slice s) x 8 batches x K=512.
// Sync: distributed store-flags (no RMW). flags[bg][layer*16+s] = rounds done.
// All B-frag IC loads hoisted before MFMAs; x prefetched under the poll.
// ---------------------------------------------------------------------------
__global__ __launch_bounds__(256, 1)
void lstm_persistent(const float* __restrict__ x,
                     const unsigned short* __restrict__ Wt2,
                     const float* __restrict__ bias_r,
                     u64* __restrict__ h1hi, u64* __restrict__ h1lo,
                     u64* __restrict__ h2hi, u64* __restrict__ h2lo,
                     int* __restrict__ cnt)
{
    __shared__ __align__(16) f32x4 red[12][64];    // cross-wave partials, 12 KB

    const int tid   = threadIdx.x;
    const int wg    = blockIdx.x;
    const int layer = wg >> 7;
    const int g     = wg & 127;
    const int bg    = g & 7;
    const int s     = g >> 3;
    const int b0    = bg * 8;
    const int wave  = tid >> 6;
    const int lane  = tid & 63;
    const int kg    = lane >> 4;       // k-group within frag
    const int rw    = lane & 15;       // row-within-tile / batch col
    const int rb    = rw & 7;          // duplicated batch for lanes 8..15
    const int batch = b0 + rb;
    int* const flags  = cnt + bg * 64;       // 32 dwords used per bg
    const int  myflag = layer * 16 + s;

    // ---- one-time: A-fragments (weights) into registers ----
    short8v Ahi[4][4], Alo[4][4];      // [mt][k2]
    #pragma unroll
    for (int mt = 0; mt < 4; ++mt)
        #pragma unroll
        for (int k2 = 0; k2 < 4; ++k2) {
            size_t base = (((size_t)((layer * 16 + s) * 4 + mt) * 16 + (wave * 4 + k2)) * 1024)
                          + (size_t)kg * 128 + rw * 8;
            Ahi[mt][k2] = *(const short8v*)((const short*)Wt2 + base);
            Alo[mt][k2] = *(const short8v*)((const short*)Wt2 + base + 512);
        }

    f32x4 biasv[4];
    #pragma unroll
    for (int mt = 0; mt < 4; ++mt)
        biasv[mt] = *(const f32x4*)(bias_r + layer * 1024 + s * 64 + mt * 16 + kg * 4);

    f32x4 creg = {0.f, 0.f, 0.f, 0.f};             // cell state (wave 0, rw<8)

    // ---- initial x prefetch (t=0), layer-0 waves 0/1 only ----
    float4 xr[4][2];
    if (layer == 0 && wave < 2) {
        #pragma unroll
        for (int k2 = 0; k2 < 4; ++k2) {
            const int kbase = (wave * 4 + k2) * 32 + kg * 8;
            const float* xp = x + ((size_t)batch * LT + 0) * LH + kbase;
            xr[k2][0] = *(const float4*)xp;
            xr[k2][1] = *(const float4*)(xp + 4);
        }
    }

    for (int r = 0; r <= LT; ++r) {
        const bool active = (layer == 0) ? (r < LT) : (r >= 1);
        const int t = (layer == 0) ? r : (r - 1);

        // ---- gather B-fragments (all loads hoisted & in flight together) ----
        short8v Bhi[4], Blo[4];
        bool useB = false;
        if (active) {
            if (layer == 0 && wave < 2) {
                // x part from prefetch registers: convert to split bf16
                #pragma unroll
                for (int k2 = 0; k2 < 4; ++k2) {
                    float fv[8] = {xr[k2][0].x, xr[k2][0].y, xr[k2][0].z, xr[k2][0].w,
                                   xr[k2][1].x, xr[k2][1].y, xr[k2][1].z, xr[k2][1].w};
                    short8v bh, bl;
                    #pragma unroll
                    for (int j = 0; j < 8; ++j) {
                        short hb = bf16_rne(fv[j]);
                        bh[j] = hb;
                        bl[j] = bf16_rne(fv[j] - bf16_to_f(hb));
                    }
                    Bhi[k2] = bh; Blo[k2] = bl;
                }
                useB = true;
            } else {
                const u64 *ph, *pl; size_t slotoff; int kofs; bool any;
                if (layer == 0) {              // waves 2,3: own h1(t-1)
                    any = (t > 0); ph = h1hi; pl = h1lo;
                    slotoff = (size_t)((t - 1) & 1) * 4096; kofs = -256;
                } else if (wave < 2) {         // layer 1 input: h1(t)
                    any = true;    ph = h1hi; pl = h1lo;
                    slotoff = (size_t)(t & 1) * 4096; kofs = 0;
                } else {                       // layer 1 recurrent: h2(t-1)
                    any = (t > 0); ph = h2hi; pl = h2lo;
                    slotoff = (size_t)((t - 1) & 1) * 4096; kofs = -256;
                }
                if (any) {
                    u64 qh[4][2], ql[4][2];
                    #pragma unroll
                    for (int k2 = 0; k2 < 4; ++k2) {   // 16 loads, one latency
                        const int kbase = (wave * 4 + k2) * 32 + kg * 8 + kofs;
                        size_t qi = slotoff + (size_t)batch * 64 + (kbase >> 2);
                        qh[k2][0] = LD_IC(ph + qi);
                        qh[k2][1] = LD_IC(ph + qi + 1);
                        ql[k2][0] = LD_IC(pl + qi);
                        ql[k2][1] = LD_IC(pl + qi + 1);
                    }
                    #pragma unroll
                    for (int k2 = 0; k2 < 4; ++k2) {
                        union { u64 q[2]; short8v v; } ch, cl;
                        ch.q[0] = qh[k2][0]; ch.q[1] = qh[k2][1];
                        cl.q[0] = ql[k2][0]; cl.q[1] = ql[k2][1];
                        Bhi[k2] = ch.v; Blo[k2] = cl.v;
                    }
                    useB = true;
                }
            }
        }

        // ---- MFMA chain ----
        f32x4 acc[4];
        #pragma unroll
        for (int mt = 0; mt < 4; ++mt) acc[mt] = (f32x4){0.f, 0.f, 0.f, 0.f};
        if (useB) {
            #pragma unroll
            for (int k2 = 0; k2 < 4; ++k2)
                #pragma unroll
                for (int mt = 0; mt < 4; ++mt) {
                    acc[mt] = MFMA(Ahi[mt][k2], Bhi[k2], acc[mt]);  // hi*hi
                    acc[mt] = MFMA(Ahi[mt][k2], Blo[k2], acc[mt]);  // hi*lo
                    acc[mt] = MFMA(Alo[mt][k2], Bhi[k2], acc[mt]);  // lo*hi
                }
        }

        // ---- cross-wave k-reduction via LDS ----
        if (active && wave > 0) {
            #pragma unroll
            for (int mt = 0; mt < 4; ++mt) red[(wave - 1) * 4 + mt][lane] = acc[mt];
        }
        __syncthreads();

        if (active && wave == 0) {
            f32x4 gate[4];
            #pragma unroll
            for (int mt = 0; mt < 4; ++mt) {
                f32x4 gs = acc[mt] + biasv[mt];
                #pragma unroll
                for (int w = 0; w < 3; ++w) gs += red[w * 4 + mt][lane];
                gate[mt] = gs;
            }
            // lane holds gates i,f,g,o (mt=0..3) for batch rw, hid = s*16+kg*4+rr
            float hv[4];
            #pragma unroll
            for (int rr = 0; rr < 4; ++rr) {
                float si = fsigm(gate[0][rr]);
                float sf = fsigm(gate[1][rr]);
                float so = fsigm(gate[3][rr]);
                float gg = ftanh(gate[2][rr]);
                float cn = sf * creg[rr] + si * gg;
                creg[rr] = cn;
                hv[rr] = so * ftanh(cn);
            }
            if (rw < 8) {
                u64 qh = 0, ql = 0;
                #pragma unroll
                for (int rr = 0; rr < 4; ++rr) {
                    short hb = bf16_rne(hv[rr]);
                    short lb = bf16_rne(hv[rr] - bf16_to_f(hb));
                    qh |= ((u64)(unsigned short)hb) << (16 * rr);
                    ql |= ((u64)(unsigned short)lb) << (16 * rr);
                }
                u64* dh = (layer == 0 ? h1hi : h2hi);
                u64* dl = (layer == 0 ? h1lo : h2lo);
                size_t qi = (size_t)(t & 1) * 4096 + (size_t)(b0 + rw) * 64 + (s * 4 + kg);
                ST_IC(dh + qi, qh);
                ST_IC(dl + qi, ql);
            }
        }

        // ---- signal: my round r done (h stores drained first) ----
        if (wave == 0 && r < LT) {
            asm volatile("s_waitcnt vmcnt(0)" ::: "memory");   // h stores acked at IC
            if (lane == 0) ST_IC(&flags[myflag], r + 1);
        }

        // ---- x prefetch for next round (independent of flags; hides HBM) ----
        if (layer == 0 && wave < 2 && t + 1 < LT) {
            #pragma unroll
            for (int k2 = 0; k2 < 4; ++k2) {
                const int kbase = (wave * 4 + k2) * 32 + kg * 8;
                const float* xp = x + ((size_t)batch * LT + (t + 1)) * LH + kbase;
                xr[k2][0] = *(const float4*)xp;
                xr[k2][1] = *(const float4*)(xp + 4);
            }
        }

        // ---- wait: all 32 WGs of this bg (both layers) done with round r ----
        if (r < LT) {
            if (wave == 0) {
                const int target = r + 1;
                const int* fp = flags + (lane & 31);
                for (;;) {
                    int v = (lane < 32) ? LD_IC(fp) : target;
                    if (__all(v >= target)) break;
                    __builtin_amdgcn_s_sleep(1);
                }
            }
            __syncthreads();
        }
    }
}

// ---------------------------------------------------------------------------
// Epilogue: out = h2(2047) @ W_fc^T + b_fc   (h2 reconstructed from hi+lo)
// ---------------------------------------------------------------------------
__global__ __launch_bounds__(256)
void fc_kernel(const unsigned short* __restrict__ h2hi_s,
               const unsigned short* __restrict__ h2lo_s,
               const float* __restrict__ W_fc,
               const float* __restrict__ b_fc,
               float* __restrict__ out) {
    int b = blockIdx.x;
    int o = threadIdx.x;
    __shared__ float hrow[LH];
    for (int k = threadIdx.x; k < LH; k += 256) {
        int idx = 16384 /*slot1*/ + b * 256 + k;
        hrow[k] = bf16_to_f((short)h2hi_s[idx]) + bf16_to_f((short)h2lo_s[idx]);
    }
    __syncthreads();
    float acc = b_fc[o];
#pragma unroll 8
    for (int k = 0; k < LH; ++k)
        acc = fmaf(W_fc[o * LH + k], hrow[k], acc);
    out[b * LOUT + o] = acc;
}

extern "C" void kernel_launch(void* const* d_in, const int* in_sizes, int n_in,
                              void* d_out, int out_size, void* d_ws, size_t ws_size,
                              hipStream_t stream) {
    const float* x    = (const float*)d_in[0];
    const float* W_ih = (const float*)d_in[1];
    const float* W_hh = (const float*)d_in[2];
    const float* b_ih = (const float*)d_in[3];
    const float* b_hh = (const float*)d_in[4];
    const float* W_fc = (const float*)d_in[5];
    const float* b_fc = (const float*)d_in[6];
    float* out = (float*)d_out;

    char* ws = (char*)d_ws;
    int*            cnt    = (int*)(ws + WS_CNT);
    u64*            h1hi   = (u64*)(ws + WS_H1HI);
    u64*            h1lo   = (u64*)(ws + WS_H1LO);
    u64*            h2hi   = (u64*)(ws + WS_H2HI);
    u64*            h2lo   = (u64*)(ws + WS_H2LO);
    float*          bias_r = (float*)(ws + WS_BIAS);
    unsigned short* Wt2    = (unsigned short*)(ws + WS_WT2);

    hipMemsetAsync(cnt, 0, WS_CNT_SZ, stream);   // fresh flags each call
    prep_weights<<<(1 << 20) / 256, 256, 0, stream>>>(W_ih, W_hh, b_ih, b_hh, Wt2, bias_r);

    void* args[] = {(void*)&x, (void*)&Wt2, (void*)&bias_r,
                    (void*)&h1hi, (void*)&h1lo, (void*)&h2hi, (void*)&h2lo, (void*)&cnt};
    hipError_t e = hipLaunchCooperativeKernel(lstm_persistent, dim3(NWG), dim3(256),
                                              args, 0, stream);
    if (e != hipSuccess) {
        // GPU otherwise idle, 1 WG/CU: 256 WGs co-reside anyway
        lstm_persistent<<<NWG, 256, 0, stream>>>(x, Wt2, bias_r, h1hi, h1lo, h2hi, h2lo, cnt);
    }

    fc_kernel<<<LB, 256, 0, stream>>>((const unsigned short*)h2hi,
                                      (const unsigned short*)h2lo, W_fc, b_fc, out);
}

// Round 6
// 8512.605 us; speedup vs baseline: 6.0707x; 1.2711x over previous
//
#include <hip/hip_runtime.h>
#include <math.h>

typedef unsigned long long u64;
typedef __attribute__((ext_vector_type(8))) short short8v;   // 8 bf16 = 4 VGPR
typedef __attribute__((ext_vector_type(4))) float f32x4;

#define LB 64
#define LT 2048
#define LH 256
#define LOUT 256
#define NWG 256

// ---------- ws layout (bytes) ----------
// flags: 8 bg * 32 members * 64B line each = 16 KB
#define WS_CNT    0
#define WS_CNT_SZ ((size_t)8 * 32 * 16 * sizeof(int))
// h buffers: 4 slots * 64 batch * 128 u64 (hi/lo interleaved per 4 hid) = 256 KB each
#define WS_H1     (64 * 1024)
#define WS_H2     (WS_H1 + 256 * 1024)
#define WS_BIAS   (WS_H2 + 256 * 1024)
#define WS_WT2    (1024 * 1024)          // 4 MB
#define HSLOT     8192                   // u64 per slot (64*128)

#define MFMA(a, b, c) __builtin_amdgcn_mfma_f32_16x16x32_bf16(a, b, c, 0, 0, 0)
#define LD_IC(p) __hip_atomic_load((p), __ATOMIC_RELAXED, __HIP_MEMORY_SCOPE_AGENT)
#define ST_IC(p, v) __hip_atomic_store((p), (v), __ATOMIC_RELAXED, __HIP_MEMORY_SCOPE_AGENT)

__device__ __host__ __forceinline__ short bf16_rne(float f) {
    unsigned u = __builtin_bit_cast(unsigned, f);
    unsigned r = (u + 0x7fffu + ((u >> 16) & 1u)) >> 16;
    return (short)r;
}
__device__ __forceinline__ float bf16_to_f(short s) {
    unsigned u = ((unsigned)(unsigned short)s) << 16;
    return __builtin_bit_cast(float, u);
}
__device__ __forceinline__ float fsigm(float g) {
    return __builtin_amdgcn_rcpf(1.f + __builtin_amdgcn_exp2f(g * -1.44269504f));
}
__device__ __forceinline__ float ftanh(float g) {
    return __builtin_amdgcn_rcpf(1.f + __builtin_amdgcn_exp2f(g * -2.88539008f)) * 2.f - 1.f;
}

// ---------------------------------------------------------------------------
// Prologue: split weights into hi/lo bf16 MFMA A-fragments (layout unchanged).
// ---------------------------------------------------------------------------
__global__ void prep_weights(const float* __restrict__ W_ih,
                             const float* __restrict__ W_hh,
                             const float* __restrict__ b_ih,
                             const float* __restrict__ b_hh,
                             unsigned short* __restrict__ Wt2,
                             float* __restrict__ bias_r) {
    int gid = blockIdx.x * 256 + threadIdx.x;       // 2^20 positions
    if (gid >= (1 << 20)) return;
    int j   = gid & 7;
    int rwi = (gid >> 3) & 15;
    int kgi = (gid >> 7) & 3;
    int ks  = (gid >> 9) & 15;
    int mt  = (gid >> 13) & 3;
    int s   = (gid >> 15) & 15;
    int layer = gid >> 19;
    int k   = ks * 32 + kgi * 8 + j;
    int row = mt * 256 + s * 16 + rwi;              // original gate row
    float w = (k < 256) ? W_ih[((size_t)layer * 1024 + row) * 256 + k]
                        : W_hh[((size_t)layer * 1024 + row) * 256 + (k - 256)];
    short hi = bf16_rne(w);
    float rem = w - bf16_to_f(hi);
    short lo = bf16_rne(rem);
    size_t base = (((size_t)((layer * 16 + s) * 4 + mt) * 16 + ks) * 1024)
                  + (size_t)kgi * 128 + rwi * 8 + j;
    Wt2[base]       = (unsigned short)hi;
    Wt2[base + 512] = (unsigned short)lo;
    if (k == 0) {
        int ridx = s * 64 + mt * 16 + rwi;
        bias_r[layer * 1024 + ridx] = b_ih[layer * 1024 + row] + b_hh[layer * 1024 + row];
    }
}

// ---------------------------------------------------------------------------
// Persistent 2-layer LSTM, MFMA split-bf16. 256 WGs (128/layer), 1/CU.
// Sync: one 64B cache line per flag; per-layer wait predicates; 4-deep
// h slot buffers let layer 0 run up to 2 rounds ahead of layer 1.
// h layout (u64): [slot(4)][batch(64)][hid4 g(64)][part(2: hi,lo)]
// ---------------------------------------------------------------------------
__global__ __launch_bounds__(256, 1)
void lstm_persistent(const float* __restrict__ x,
                     const unsigned short* __restrict__ Wt2,
                     const float* __restrict__ bias_r,
                     u64* __restrict__ h1, u64* __restrict__ h2,
                     int* __restrict__ cnt)
{
    __shared__ __align__(16) f32x4 red[12][64];    // cross-wave partials, 12 KB

    const int tid   = threadIdx.x;
    const int wg    = blockIdx.x;
    const int layer = wg >> 7;
    const int g     = wg & 127;
    const int bg    = g & 7;
    const int s     = g >> 3;
    const int b0    = bg * 8;
    const int wave  = tid >> 6;
    const int lane  = tid & 63;
    const int kg    = lane >> 4;       // k-group within frag
    const int rw    = lane & 15;       // row-within-tile / batch col
    const int rb    = rw & 7;          // duplicated batch for lanes 8..15
    const int batch = b0 + rb;
    int* const fl_base = cnt + (size_t)bg * 32 * 16;   // 32 lines for this bg
    const int  myflag  = (layer * 16 + s) * 16;

    // ---- one-time: A-fragments (weights) into registers ----
    short8v Ahi[4][4], Alo[4][4];      // [mt][k2]
    #pragma unroll
    for (int mt = 0; mt < 4; ++mt)
        #pragma unroll
        for (int k2 = 0; k2 < 4; ++k2) {
            size_t base = (((size_t)((layer * 16 + s) * 4 + mt) * 16 + (wave * 4 + k2)) * 1024)
                          + (size_t)kg * 128 + rw * 8;
            Ahi[mt][k2] = *(const short8v*)((const short*)Wt2 + base);
            Alo[mt][k2] = *(const short8v*)((const short*)Wt2 + base + 512);
        }

    f32x4 biasv[4];
    #pragma unroll
    for (int mt = 0; mt < 4; ++mt)
        biasv[mt] = *(const f32x4*)(bias_r + layer * 1024 + s * 64 + mt * 16 + kg * 4);

    f32x4 creg = {0.f, 0.f, 0.f, 0.f};             // cell state (wave 0, rw<8)

    // ---- initial x prefetch (t=0), layer-0 waves 0/1 only ----
    float4 xr[4][2];
    if (layer == 0 && wave < 2) {
        #pragma unroll
        for (int k2 = 0; k2 < 4; ++k2) {
            const int kbase = (wave * 4 + k2) * 32 + kg * 8;
            const float* xp = x + ((size_t)batch * LT + 0) * LH + kbase;
            xr[k2][0] = *(const float4*)xp;
            xr[k2][1] = *(const float4*)(xp + 4);
        }
    }

    for (int r = 0; r <= LT; ++r) {
        const bool active = (layer == 0) ? (r < LT) : (r >= 1);
        const int t = (layer == 0) ? r : (r - 1);

        // ---- gather B-fragments (all loads issued together) ----
        short8v Bhi[4], Blo[4];
        bool useB = false;
        if (active) {
            if (layer == 0 && wave < 2) {
                // x part from prefetch registers: convert to split bf16
                #pragma unroll
                for (int k2 = 0; k2 < 4; ++k2) {
                    float fv[8] = {xr[k2][0].x, xr[k2][0].y, xr[k2][0].z, xr[k2][0].w,
                                   xr[k2][1].x, xr[k2][1].y, xr[k2][1].z, xr[k2][1].w};
                    short8v bh, bl;
                    #pragma unroll
                    for (int j = 0; j < 8; ++j) {
                        short hb = bf16_rne(fv[j]);
                        bh[j] = hb;
                        bl[j] = bf16_rne(fv[j] - bf16_to_f(hb));
                    }
                    Bhi[k2] = bh; Blo[k2] = bl;
                }
                useB = true;
            } else {
                const u64* hb; size_t slotbase; int kofs; bool any;
                if (layer == 0) {              // waves 2,3: own h1(t-1)
                    any = (t > 0); hb = h1; slotbase = (size_t)((t - 1) & 3) * HSLOT; kofs = -256;
                } else if (wave < 2) {         // layer 1 input: h1(t)
                    any = true;    hb = h1; slotbase = (size_t)(t & 3) * HSLOT; kofs = 0;
                } else {                       // layer 1 recurrent: h2(t-1)
                    any = (t > 0); hb = h2; slotbase = (size_t)((t - 1) & 3) * HSLOT; kofs = -256;
                }
                if (any) {
                    u64 q[4][4];
                    #pragma unroll
                    for (int k2 = 0; k2 < 4; ++k2) {   // 16 loads, one latency
                        const int kbase = (wave * 4 + k2) * 32 + kg * 8 + kofs;
                        size_t qi = slotbase + (size_t)batch * 128 + (kbase >> 2) * 2;
                        q[k2][0] = LD_IC(hb + qi);
                        q[k2][1] = LD_IC(hb + qi + 1);
                        q[k2][2] = LD_IC(hb + qi + 2);
                        q[k2][3] = LD_IC(hb + qi + 3);
                    }
                    #pragma unroll
                    for (int k2 = 0; k2 < 4; ++k2) {
                        union { u64 qq[2]; short8v v; } ch, cl;
                        ch.qq[0] = q[k2][0]; ch.qq[1] = q[k2][2];
                        cl.qq[0] = q[k2][1]; cl.qq[1] = q[k2][3];
                        Bhi[k2] = ch.v; Blo[k2] = cl.v;
                    }
                    useB = true;
                }
            }
        }

        // ---- MFMA chain ----
        f32x4 acc[4];
        #pragma unroll
        for (int mt = 0; mt < 4; ++mt) acc[mt] = (f32x4){0.f, 0.f, 0.f, 0.f};
        if (useB) {
            #pragma unroll
            for (int k2 = 0; k2 < 4; ++k2)
                #pragma unroll
                for (int mt = 0; mt < 4; ++mt) {
                    acc[mt] = MFMA(Ahi[mt][k2], Bhi[k2], acc[mt]);  // hi*hi
                    acc[mt] = MFMA(Ahi[mt][k2], Blo[k2], acc[mt]);  // hi*lo
                    acc[mt] = MFMA(Alo[mt][k2], Bhi[k2], acc[mt]);  // lo*hi
                }
        }

        // ---- cross-wave k-reduction via LDS ----
        if (active && wave > 0) {
            #pragma unroll
            for (int mt = 0; mt < 4; ++mt) red[(wave - 1) * 4 + mt][lane] = acc[mt];
        }
        __syncthreads();

        if (active && wave == 0) {
            f32x4 gate[4];
            #pragma unroll
            for (int mt = 0; mt < 4; ++mt) {
                f32x4 gs = acc[mt] + biasv[mt];
                #pragma unroll
                for (int w = 0; w < 3; ++w) gs += red[w * 4 + mt][lane];
                gate[mt] = gs;
            }
            // lane holds gates i,f,g,o (mt=0..3) for batch rw, hid = s*16+kg*4+rr
            float hv[4];
            #pragma unroll
            for (int rr = 0; rr < 4; ++rr) {
                float si = fsigm(gate[0][rr]);
                float sf = fsigm(gate[1][rr]);
                float so = fsigm(gate[3][rr]);
                float gg = ftanh(gate[2][rr]);
                float cn = sf * creg[rr] + si * gg;
                creg[rr] = cn;
                hv[rr] = so * ftanh(cn);
            }
            if (rw < 8) {
                u64 qh = 0, ql = 0;
                #pragma unroll
                for (int rr = 0; rr < 4; ++rr) {
                    short hb = bf16_rne(hv[rr]);
                    short lb = bf16_rne(hv[rr] - bf16_to_f(hb));
                    qh |= ((u64)(unsigned short)hb) << (16 * rr);
                    ql |= ((u64)(unsigned short)lb) << (16 * rr);
                }
                u64* dst = (layer == 0 ? h1 : h2);
                size_t qi = (size_t)(t & 3) * HSLOT + (size_t)(b0 + rw) * 128 + (s * 4 + kg) * 2;
                ST_IC(dst + qi, qh);       // adjacent pair: one line per batch row
                ST_IC(dst + qi + 1, ql);
            }
        }

        // ---- signal: my round r done (h stores drained first) ----
        if (wave == 0 && r < LT) {
            asm volatile("s_waitcnt vmcnt(0)" ::: "memory");   // h stores acked at IC
            if (lane == 0) ST_IC(fl_base + myflag, r + 1);
        }

        // ---- x prefetch for next round (independent of flags; hides HBM) ----
        if (layer == 0 && wave < 2 && t + 1 < LT) {
            #pragma unroll
            for (int k2 = 0; k2 < 4; ++k2) {
                const int kbase = (wave * 4 + k2) * 32 + kg * 8;
                const float* xp = x + ((size_t)batch * LT + (t + 1)) * LH + kbase;
                xr[k2][0] = *(const float4*)xp;
                xr[k2][1] = *(const float4*)(xp + 4);
            }
        }

        // ---- wait for round r+1 preconditions (per-layer predicates) ----
        // L0 entering r+1: L0 flags >= r+1, L1 flags >= r-1 (4-slot anti-dep)
        // L1 entering r+1: all 32 flags >= r+1
        if (r < LT) {
            if (wave == 0) {
                const int mL = lane >> 4;          // member's layer (lanes 0..31)
                const int tgt = (layer == 0) ? ((mL == 0) ? r + 1 : r - 1) : (r + 1);
                const int* fp = fl_base + (size_t)(lane & 31) * 16;
                for (;;) {
                    int v = (lane < 32) ? LD_IC(fp) : 0x7fffffff;
                    if (__all(v >= tgt)) break;
                    __builtin_amdgcn_s_sleep(1);
                }
            }
            __syncthreads();
        }
    }
}

// ---------------------------------------------------------------------------
// Epilogue: out = h2(2047) @ W_fc^T + b_fc   (slot 3, hi/lo interleaved)
// ---------------------------------------------------------------------------
__global__ __launch_bounds__(256)
void fc_kernel(const u64* __restrict__ h2w,
               const float* __restrict__ W_fc,
               const float* __restrict__ b_fc,
               float* __restrict__ out) {
    int b = blockIdx.x;
    int o = threadIdx.x;
    __shared__ float hrow[LH];
    for (int k = threadIdx.x; k < LH; k += 256) {
        size_t w = (size_t)3 * HSLOT + (size_t)b * 128 + (k >> 2) * 2;
        int sh = (k & 3) * 16;
        short hi = (short)((h2w[w]     >> sh) & 0xffff);
        short lo = (short)((h2w[w + 1] >> sh) & 0xffff);
        hrow[k] = bf16_to_f(hi) + bf16_to_f(lo);
    }
    __syncthreads();
    float acc = b_fc[o];
#pragma unroll 8
    for (int k = 0; k < LH; ++k)
        acc = fmaf(W_fc[o * LH + k], hrow[k], acc);
    out[b * LOUT + o] = acc;
}

extern "C" void kernel_launch(void* const* d_in, const int* in_sizes, int n_in,
                              void* d_out, int out_size, void* d_ws, size_t ws_size,
                              hipStream_t stream) {
    const float* x    = (const float*)d_in[0];
    const float* W_ih = (const float*)d_in[1];
    const float* W_hh = (const float*)d_in[2];
    const float* b_ih = (const float*)d_in[3];
    const float* b_hh = (const float*)d_in[4];
    const float* W_fc = (const float*)d_in[5];
    const float* b_fc = (const float*)d_in[6];
    float* out = (float*)d_out;

    char* ws = (char*)d_ws;
    int*            cnt    = (int*)(ws + WS_CNT);
    u64*            h1     = (u64*)(ws + WS_H1);
    u64*            h2     = (u64*)(ws + WS_H2);
    float*          bias_r = (float*)(ws + WS_BIAS);
    unsigned short* Wt2    = (unsigned short*)(ws + WS_WT2);

    hipMemsetAsync(cnt, 0, WS_CNT_SZ, stream);   // fresh flags each call
    prep_weights<<<(1 << 20) / 256, 256, 0, stream>>>(W_ih, W_hh, b_ih, b_hh, Wt2, bias_r);

    void* args[] = {(void*)&x, (void*)&Wt2, (void*)&bias_r,
                    (void*)&h1, (void*)&h2, (void*)&cnt};
    hipError_t e = hipLaunchCooperativeKernel(lstm_persistent, dim3(NWG), dim3(256),
                                              args, 0, stream);
    if (e != hipSuccess) {
        // GPU otherwise idle, 1 WG/CU: 256 WGs co-reside anyway
        lstm_persistent<<<NWG, 256, 0, stream>>>(x, Wt2, bias_r, h1, h2, cnt);
    }

    fc_kernel<<<LB, 256, 0, stream>>>(h2, W_fc, b_fc, out);
}